// Round 11
// baseline (186.268 us; speedup 1.0000x reference)
//
#include <hip/hip_runtime.h>

// ScaleDotProductAttention: B=2,H=16,S=2048,D=64 (fp32 in/out; bf16-adaptive).
// R18: fixed-cost amortization. R11-R17 plateau at ~57us: per-phase fixed cost
// (stage+barrier+ds_read+mask) ~700cy vs 340cy MFMA. Now each wave owns 64
// q-rows as TWO 32-row tiles sharing one staged k-subtile: K/V ds_reads,
// staging, barrier, mask loads amortize over 2x output (16 MFMA/phase).
// Grid 512, launch_bounds(256,2) (R13: 2 vs 4 waves/SIMD is neutral).
// Row-sums back to R11-verified VALU partials + Ls table (frees 32 VGPR +
// 4 MFMA/phase vs ones-MFMA). Combine: Cb overlay 32KB exact + Ls 1KB.

#define S_LEN 2048
#define D_DIM 64
#define WPR   32
#define NIT   32

typedef __attribute__((ext_vector_type(8)))  short bf16x8;
typedef __attribute__((ext_vector_type(4)))  float f32x4;
typedef __attribute__((ext_vector_type(16))) float f32x16;
typedef unsigned uint2v __attribute__((ext_vector_type(2)));
typedef unsigned long long ull;

__device__ __forceinline__ f32x16 mfma32(bf16x8 a, bf16x8 b, f32x16 c) {
  return __builtin_amdgcn_mfma_f32_32x32x16_bf16(a, b, c, 0, 0, 0);
}
__device__ __forceinline__ f32x4 mfma16(bf16x8 a, bf16x8 b, f32x4 c) {
  return __builtin_amdgcn_mfma_f32_16x16x32_bf16(a, b, c, 0, 0, 0);
}
__device__ __forceinline__ unsigned short f2bf(float f) {
  unsigned u = __builtin_bit_cast(unsigned, f);
  unsigned r = u + 0x7FFFu + ((u >> 16) & 1u);
  return (unsigned short)(r >> 16);
}
__device__ __forceinline__ float bf2f(unsigned short s) {
  unsigned u = ((unsigned)s) << 16;
  return __builtin_bit_cast(float, u);
}
__device__ __forceinline__ unsigned packbf(float a, float b) {
  // gfx950: v_cvt_pk_bf16_f32 (RNE), no clang builtin -> inline asm (T12).
  unsigned r;
  asm("v_cvt_pk_bf16_f32 %0, %1, %2" : "=v"(r) : "v"(a), "v"(b));
  return r;
}
__device__ __forceinline__ float fexp2(float x) {
#if __has_builtin(__builtin_amdgcn_exp2f)
  return __builtin_amdgcn_exp2f(x);
#else
  return exp2f(x);
#endif
}
__device__ __forceinline__ bool detect_bf16(const void* maskp) {
  const unsigned short* s = (const unsigned short*)maskp;
  unsigned short v = s[2 * (threadIdx.x & 63)];
  return __ballot(v == (unsigned short)0x3F80) != 0ull;
}
__device__ __forceinline__ int4 cvt_f8(const float* p) {
  float4 f0 = *(const float4*)p;
  float4 f1 = *(const float4*)(p + 4);
  int4 r;
  r.x = (int)packbf(f0.x, f0.y);
  r.y = (int)packbf(f0.z, f0.w);
  r.z = (int)packbf(f1.x, f1.y);
  r.w = (int)packbf(f1.z, f1.w);
  return r;
}
// Async 16B/lane global->LDS. g is PER-LANE src; dest = l + lane*16B (HW).
__device__ __forceinline__ void gl_lds16(const unsigned short* g, unsigned short* l) {
#if __has_builtin(__builtin_amdgcn_global_load_lds)
  __builtin_amdgcn_global_load_lds(
      (const __attribute__((address_space(1))) unsigned int*)g,
      (__attribute__((address_space(3))) unsigned int*)l, 16, 0, 0);
#else
  *(int4*)((char*)l + (threadIdx.x & 63) * 16) = *(const int4*)g;
#endif
}

#define C1 0.18033688011112042f     /* (1/sqrt(64))*log2(e) */
#define C2 1.4426950408889634e9f

#define SEG0 4096u
#define SEG1 2048u
#define SEG2 1024u
#define SEG3 2048u

// ---------------- unified prepass (R17-verified) ----------------
// seg0 (4096):  mask tile (32 rows x 64 cols) -> FINAL lane-masks (fused prep_w)
// seg1 (2048):  K -> Kf 32x32 A-frags           [skipped when bf16 inputs]
// seg2 (1024):  V -> Vf 32x32 B-frags
// seg3 (2048):  Q -> Qc bf16 row-major, *C1     [skipped when bf16 inputs]
__global__ __launch_bounds__(256) void prep_all(
    const void* __restrict__ M, const void* __restrict__ Kin,
    const void* __restrict__ Vin, const void* __restrict__ Qin,
    ull* __restrict__ bits, unsigned short* __restrict__ Kf,
    unsigned short* __restrict__ Vf, unsigned short* __restrict__ Qc) {
  __shared__ __align__(16) unsigned short T[64 * 72];
  __shared__ ull rowb[32];
  const bool isb = detect_bf16(M);
  const unsigned bx = blockIdx.x;
  const int tid = threadIdx.x;

  if (bx < SEG0) {   // ---- mask -> lane-masks, one (bb, q32, w) tile per block
    const unsigned bb = bx >> 11, q32 = (bx >> 5) & 63u, w = bx & 31u;
    const int wv = tid >> 6, l = tid & 63;
    #pragma unroll
    for (int j = 0; j < 8; ++j) {
      int rl = j * 4 + wv;                       // row_local 0..31
      size_t midx = ((size_t)(bb * 2048u + q32 * 32u + rl)) * 2048u + w * 64u + l;
      bool on = isb ? (bf2f(((const unsigned short*)M)[midx]) > 0.5f)
                    : (((const float*)M)[midx] > 0.5f);
      ull bm = __ballot(on);
      if (l == 0) rowb[rl] = bm;                 // row word: bit c = col w*64+c
    }
    __syncthreads();
    if (wv == 0) {
      const ull wc = rowb[l & 31];
      const int hi2 = l >> 5;
      ull* basep = bits + (((size_t)(bb * 32 + w)) << 11) + (size_t)q32 * 32;
      #pragma unroll
      for (int sub = 0; sub < 2; ++sub) {
        #pragma unroll
        for (int r = 0; r < 16; ++r) {
          int pos = sub * 32 + (r & 3) + 8 * (r >> 2) + 4 * hi2;
          ull W = __ballot(((wc >> pos) & 1ull) != 0ull);
          if (l == 0) basep[sub * 16 + r] = W;
        }
      }
    }
  } else if (bx < SEG0 + SEG1) {   // ---- Kf gather (fp32 inputs only)
    if (isb) return;
    unsigned g = (bx - SEG0) * 256u + tid;
    unsigned lane = g & 63u, f = (g >> 6) & 7u, it = (g >> 9) & 31u, bh = g >> 14;
    unsigned t = f >> 2, dc = f & 3, hi = lane >> 5, l31 = lane & 31;
    size_t src = (size_t)bh * (S_LEN * D_DIM) +
                 (size_t)(it * 64 + t * 32 + l31) * D_DIM + dc * 16 + hi * 8;
    *(int4*)&Kf[(size_t)g * 8] = cvt_f8((const float*)Kin + src);
  } else if (bx < SEG0 + SEG1 + SEG2) {  // ---- Vf transpose via LDS
    unsigned idx = bx - (SEG0 + SEG1);
    unsigned bh = idx >> 5, it = idx & 31u;
    {
      int k = tid >> 2, d0 = (tid & 3) * 16;
      size_t src = (size_t)bh * (S_LEN * D_DIM) + (size_t)(it * 64 + k) * D_DIM + d0;
      int4 a, c;
      if (isb) {
        const unsigned short* s = (const unsigned short*)Vin + src;
        a = *(const int4*)s; c = *(const int4*)(s + 8);
      } else {
        const float* s = (const float*)Vin + src;
        a = cvt_f8(s); c = cvt_f8(s + 8);
      }
      *(int4*)&T[k * 72 + d0] = a;
      *(int4*)&T[k * 72 + d0 + 8] = c;
    }
    __syncthreads();
    #pragma unroll
    for (int h = 0; h < 2; ++h) {
      int c = tid + h * 256;
      int lane = c & 63, f = c >> 6;
      int t = f >> 2, kc = (f >> 1) & 1, dt = f & 1;
      int hi = lane >> 5, l31 = lane & 31;
      unsigned short v[8];
      #pragma unroll
      for (int j = 0; j < 8; ++j)
        v[j] = T[(t * 32 + kc * 16 + hi * 8 + j) * 72 + dt * 32 + l31];
      *(int4*)&Vf[(((size_t)(bh * 32 + it)) * 8 + f) * 512 + lane * 8] = *(int4*)v;
    }
  } else {                       // ---- Qc (fp32 inputs only)
    if (isb) return;
    size_t i0 = ((size_t)(bx - (SEG0 + SEG1 + SEG2)) * 256 + tid) * 8;
    unsigned short v[8];
    const float* f = (const float*)Qin + i0;
    #pragma unroll
    for (int j = 0; j < 4; ++j)
      *((unsigned*)v + j) = packbf(f[2 * j] * C1, f[2 * j + 1] * C1);
    *(int4*)&Qc[i0] = *(int4*)v;
  }
}

// ---------------- split-K attention, 64 q-rows/wave (2 tiles) ----------------
// grid 512: id -> xcd=id&7, slot=id>>3; bh=(id&7)*4+(slot&3); qb=slot>>2 (0..15).
// Block = 128 q-rows. Wave w: g=w>>1 sweeps subtiles [g*32,+32); rw=w&1 picks
// 64-row half; tiles u=0,1 are 32-row subtiles sharing the staged k-subtile.
// Mask: per-phase wave-uniform lane-mask ulls (s_load) + v_cndmask.
__global__ __launch_bounds__(256, 2) void attn_fast(
    const unsigned short* __restrict__ Qc, const void* __restrict__ Qraw,
    const unsigned short* __restrict__ Kf, const void* __restrict__ Kraw,
    const unsigned short* __restrict__ Vf, const ull* __restrict__ Wm,
    const void* __restrict__ maskp, void* __restrict__ Op) {
  __shared__ __align__(16) unsigned short Stg[2][2][8][512]; // 32KB [grp][buf][frag][1KB]
  __shared__ float Ls[4][2][32];                              // 1KB row-sums

  const bool isb = detect_bf16(maskp);
  const int tid  = threadIdx.x;
  const int wave = tid >> 6;
  const int lane = tid & 63;
  const int hi   = lane >> 5;
  const int l31  = lane & 31;
  const int wvu  = __builtin_amdgcn_readfirstlane(wave);
  const int g    = wvu >> 1;        // k-half (uniform)
  const int rw   = wvu & 1;         // row-half (uniform)
  const int id   = blockIdx.x;
  const int slot = id >> 3;
  const int bh   = (id & 7) * 4 + (slot & 3);   // XCD-affine: 4 bh per XCD
  const int qb   = slot >> 2;                   // 0..15
  const int qbase = qb * 128 + rw * 64;         // wave's 64 rows (tile u adds u*32)
  const int b    = bh >> 4;
  const size_t base = (size_t)bh * S_LEN * D_DIM;
  const int xidx = ((lane ^ 32) & 63) * 4;      // ds_bpermute byte index

  // Q B-fragments for both tiles: bf16, scaled by C1
  bf16x8 qf[2][4];
  if (isb) {
    #pragma unroll
    for (int u = 0; u < 2; ++u)
      #pragma unroll
      for (int dc = 0; dc < 4; ++dc) {
        bf16x8 q = *(const bf16x8*)((const unsigned short*)Qraw + base +
                      (size_t)(qbase + u * 32 + l31) * D_DIM + dc * 16 + hi * 8);
        #pragma unroll
        for (int j = 0; j < 8; ++j)
          q[j] = (short)f2bf(bf2f((unsigned short)q[j]) * C1);
        qf[u][dc] = q;
      }
  } else {
    #pragma unroll
    for (int u = 0; u < 2; ++u)
      #pragma unroll
      for (int dc = 0; dc < 4; ++dc)
        qf[u][dc] = *(const bf16x8*)&Qc[base +
                      (size_t)(qbase + u * 32 + l31) * D_DIM + dc * 16 + hi * 8];
  }

  // K staging source: per-lane gather (bf16 direct) or Kf linear (fp32 path).
  const unsigned short* Kw0;
  size_t kd;
  if (isb) {
    Kw0 = (const unsigned short*)Kraw + base + (size_t)l31 * D_DIM + (2 * rw) * 16 + hi * 8;
    kd = 16;
  } else {
    Kw0 = Kf + (size_t)bh * 131072 + (size_t)(2 * rw) * 512 + lane * 8;
    kd = 512;
  }
  const unsigned short* Vw = Vf + (size_t)bh * 131072 + (size_t)(2 * rw) * 512 + lane * 8;
  const int ks0 = g * 32;

  // wave-uniform lane-mask base; tile u at q32 = qb*4 + rw*2 + u
  const ull* WmU0 = Wm + (((size_t)(b * 32)) << 11) + (size_t)(qb * 4 + rw * 2) * 32;

  f32x16 acc_o[2][2];  // [u][dt]: O[m=(reg&3)+8(reg>>2)+4hi][d=dt*32+l31] (unnorm)
  f32x16 zv;           // persistent zero C-operand
  float ls[2][4];      // per-tile row-sum partials (VALU, R11-verified)
  #pragma unroll
  for (int r = 0; r < 16; ++r) {
    acc_o[0][0][r] = 0.f; acc_o[0][1][r] = 0.f;
    acc_o[1][0][r] = 0.f; acc_o[1][1][r] = 0.f;
    zv[r] = 0.f;
  }
  #pragma unroll
  for (int u = 0; u < 2; ++u)
    #pragma unroll
    for (int j = 0; j < 4; ++j) ls[u][j] = 0.f;

  // prologue: stage subtile ks0 into buf 0
  {
    const size_t so = (size_t)ks0 * 2048;
    gl_lds16(Kw0 + so,      &Stg[g][0][2 * rw][0]);
    gl_lds16(Kw0 + so + kd, &Stg[g][0][2 * rw + 1][0]);
    gl_lds16(Vw + so,       &Stg[g][0][4 + 2 * rw][0]);
    gl_lds16(Vw + so + 512, &Stg[g][0][4 + 2 * rw + 1][0]);
  }
  __syncthreads();

  #pragma unroll 2
  for (int f = 0; f < 32; ++f) {
    const int cur = f & 1;
    // stage next subtile into the other buffer (flies under this compute)
    if (f < 31) {
      const size_t so = (size_t)(ks0 + f + 1) * 2048;
      gl_lds16(Kw0 + so,      &Stg[g][cur ^ 1][2 * rw][0]);
      gl_lds16(Kw0 + so + kd, &Stg[g][cur ^ 1][2 * rw + 1][0]);
      gl_lds16(Vw + so,       &Stg[g][cur ^ 1][4 + 2 * rw][0]);
      gl_lds16(Vw + so + 512, &Stg[g][cur ^ 1][4 + 2 * rw + 1][0]);
    }
    const int ks = ks0 + f;
    const ull* Wp0 = WmU0 + (((size_t)(ks >> 1)) << 11) + (size_t)(ks & 1) * 16;

    // shared K and V fragments for both q-tiles (amortized ds_read)
    bf16x8 ka[4], vf4[4];
    #pragma unroll
    for (int dc = 0; dc < 4; ++dc) {
      ka[dc]  = *(const bf16x8*)&Stg[g][cur][dc][lane * 8];
      vf4[dc] = *(const bf16x8*)&Stg[g][cur][4 + dc][lane * 8];
    }

    #pragma unroll
    for (int u = 0; u < 2; ++u) {
      const ull* Wp = Wp0 + u * 32;
      // QK^T: two independent 2-deep chains
      __builtin_amdgcn_s_setprio(1);
      f32x16 s0 = mfma32(ka[0], qf[u][0], zv);
      f32x16 s1 = mfma32(ka[2], qf[u][2], zv);
      s0 = mfma32(ka[1], qf[u][1], s0);
      s1 = mfma32(ka[3], qf[u][3], s1);
      __builtin_amdgcn_s_setprio(0);

      // merge + exp2 + mask (one cndmask per slot, SGPR-pair mask)
      float p[16];
      #pragma unroll
      for (int r = 0; r < 16; ++r) {
        float e = fexp2(s0[r] + s1[r]);
        ull mr = Wp[r];
        asm("v_cndmask_b32 %0, %1, 0, %2" : "=v"(p[r]) : "v"(e), "s"(mr));
      }
      ls[u][0] += p[0] + p[4] + p[8]  + p[12];
      ls[u][1] += p[1] + p[5] + p[9]  + p[13];
      ls[u][2] += p[2] + p[6] + p[10] + p[14];
      ls[u][3] += p[3] + p[7] + p[11] + p[15];

      #pragma unroll
      for (int kc = 0; kc < 2; ++kc) {
        unsigned pk0 = packbf(p[8 * kc + 0], p[8 * kc + 1]);
        unsigned pk1 = packbf(p[8 * kc + 2], p[8 * kc + 3]);
        unsigned pk2 = packbf(p[8 * kc + 4], p[8 * kc + 5]);
        unsigned pk3 = packbf(p[8 * kc + 6], p[8 * kc + 7]);
        uint4 d;
#if __has_builtin(__builtin_amdgcn_permlane32_swap)
        uint2v s02 = __builtin_amdgcn_permlane32_swap(pk0, pk2, false, false);
        uint2v s13 = __builtin_amdgcn_permlane32_swap(pk1, pk3, false, false);
        d.x = s02[0]; d.z = s02[1];
        d.y = s13[0]; d.w = s13[1];
#else
        unsigned x0 = (unsigned)__builtin_amdgcn_ds_bpermute(xidx, (int)pk0);
        unsigned x1 = (unsigned)__builtin_amdgcn_ds_bpermute(xidx, (int)pk1);
        unsigned x2 = (unsigned)__builtin_amdgcn_ds_bpermute(xidx, (int)pk2);
        unsigned x3 = (unsigned)__builtin_amdgcn_ds_bpermute(xidx, (int)pk3);
        d.x = hi ? x2 : pk0;
        d.y = hi ? x3 : pk1;
        d.z = hi ? pk2 : x0;
        d.w = hi ? pk3 : x1;
#endif
        bf16x8 pf = __builtin_bit_cast(bf16x8, d);
        __builtin_amdgcn_s_setprio(1);
        acc_o[u][0] = mfma32(pf, vf4[kc * 2 + 0], acc_o[u][0]);
        acc_o[u][1] = mfma32(pf, vf4[kc * 2 + 1], acc_o[u][1]);
        __builtin_amdgcn_s_setprio(0);
      }
    }

    // one barrier per phase: next stage landed + buf[cur] safe to restage
    __syncthreads();
  }

  // ---- row sums: partner hi-half add, then per-wave Ls table
  #pragma unroll
  for (int u = 0; u < 2; ++u) {
    float lsum = (ls[u][0] + ls[u][1]) + (ls[u][2] + ls[u][3]);
    int li = __builtin_bit_cast(int, lsum);
    float other = __builtin_bit_cast(float, __builtin_amdgcn_ds_bpermute(xidx, li));
    lsum += other;
    if (hi == 0) Ls[wave][u][l31] = lsum;
  }

  // ---- cross-group combine via retired Stg (fixed-max softmax -> pure sums)
  float* Cb = (float*)Stg;   // [rw*64 + u*32 + dt*16 + r][lane] = 32KB exact
  if (g == 1) {
    #pragma unroll
    for (int u = 0; u < 2; ++u)
      #pragma unroll
      for (int dt = 0; dt < 2; ++dt)
        #pragma unroll
        for (int r = 0; r < 16; ++r)
          Cb[((size_t)(rw * 64 + u * 32 + dt * 16 + r)) * 64 + lane] = acc_o[u][dt][r];
  }
  __syncthreads();
  if (g == 0) {
    #pragma unroll
    for (int u = 0; u < 2; ++u)
      #pragma unroll
      for (int r = 0; r < 16; ++r) {
        int m = (r & 3) + 8 * (r >> 2) + 4 * hi;
        float lv = Ls[wave][u][m] + Ls[wave + 2][u][m];
        float inv = 1.0f / lv;
        float o0 = acc_o[u][0][r] + Cb[((size_t)(rw * 64 + u * 32 + r)) * 64 + lane];
        float o1 = acc_o[u][1][r] + Cb[((size_t)(rw * 64 + u * 32 + 16 + r)) * 64 + lane];
        size_t idx = base + (size_t)(qbase + u * 32 + m) * D_DIM + l31;
        if (isb) {
          ((unsigned short*)Op)[idx]      = f2bf(o0 * inv);
          ((unsigned short*)Op)[idx + 32] = f2bf(o1 * inv);
        } else {
          ((float*)Op)[idx]      = o0 * inv;
          ((float*)Op)[idx + 32] = o1 * inv;
        }
      }
  }
}

// ---------------- no-workspace fallback (R2-proven structure) ----------------
__global__ __launch_bounds__(256, 2) void attn_fallback(
    const void* __restrict__ Qp, const void* __restrict__ Kp,
    const void* __restrict__ Vp, const void* __restrict__ maskp,
    void* __restrict__ Op) {
  __shared__ __align__(16) short QKlds[128 * 72];
  __shared__ __align__(16) short Vtlds[64 * 72];
  __shared__ __align__(16) short Plds2[128 * 72];

  const bool isb = detect_bf16(maskp);
  const int tid  = threadIdx.x;
  const int wave = tid >> 6;
  const int lane = tid & 63;
  const int l15  = lane & 15;
  const int quad = lane >> 4;
  const int q0   = blockIdx.x * 128;
  const int bh   = blockIdx.y;
  const int b    = bh >> 4;
  const size_t base = (size_t)bh * S_LEN * D_DIM;

  const short* Qs = (const short*)Qp; const float* Qf = (const float*)Qp;
  const short* Ks = (const short*)Kp; const float* Kf2 = (const float*)Kp;
  const short* Vs = (const short*)Vp; const float* Vf2 = (const float*)Vp;

  if (isb) {
    const short* Qg = Qs + base + (size_t)q0 * D_DIM;
    #pragma unroll
    for (int p = 0; p < 4; ++p) {
      int e = p * 2048 + tid * 8;
      *(int4*)&QKlds[(e >> 6) * 72 + (e & 63)] = *(const int4*)(Qg + e);
    }
  } else {
    const float* Qg = Qf + base + (size_t)q0 * D_DIM;
    #pragma unroll
    for (int p = 0; p < 4; ++p) {
      int e = p * 2048 + tid * 8;
      *(int4*)&QKlds[(e >> 6) * 72 + (e & 63)] = cvt_f8(Qg + e);
    }
  }
  __syncthreads();
  bf16x8 qf[2][2];
  #pragma unroll
  for (int mi = 0; mi < 2; ++mi)
    #pragma unroll
    for (int kt = 0; kt < 2; ++kt)
      qf[mi][kt] = *(const bf16x8*)&QKlds[(wave * 32 + mi * 16 + l15) * 72 + kt * 32 + quad * 8];
  __syncthreads();

  f32x4 acc_o[2][4];
  f32x4 acc_l[2];
  const f32x4 zero4 = {0.f, 0.f, 0.f, 0.f};
  #pragma unroll
  for (int mi = 0; mi < 2; ++mi) {
    acc_l[mi] = zero4;
    #pragma unroll
    for (int nt = 0; nt < 4; ++nt) acc_o[mi][nt] = zero4;
  }
  bf16x8 onesB;
  {
    short ov = (l15 == 0) ? (short)0x3F80 : (short)0;
    #pragma unroll
    for (int i = 0; i < 8; ++i) onesB[i] = ov;
  }

  for (int it = 0; it < NIT; ++it) {
    const int k0 = it * 64;
    if (isb) {
      const short* Kg = Ks + base + (size_t)k0 * D_DIM;
      #pragma unroll
      for (int p = 0; p < 2; ++p) {
        int e = p * 2048 + tid * 8;
        *(int4*)&QKlds[(e >> 6) * 72 + (e & 63)] = *(const int4*)(Kg + e);
      }
    } else {
      const float* Kg = Kf2 + base + (size_t)k0 * D_DIM;
      #pragma unroll
      for (int p = 0; p < 2; ++p) {
        int e = p * 2048 + tid * 8;
        *(int4*)&QKlds[(e >> 6) * 72 + (e & 63)] = cvt_f8(Kg + e);
      }
    }
    {
      const int r0 = (tid >> 3) * 2;
      const int d0 = (tid & 7) * 8;
      unsigned short as_[8], bs_[8];
      if (isb) {
        const short* Vg = Vs + base + (size_t)k0 * D_DIM;
        *(int4*)as_ = *(const int4*)(Vg + r0 * D_DIM + d0);
        *(int4*)bs_ = *(const int4*)(Vg + (r0 + 1) * D_DIM + d0);
      } else {
        const float* Vg = Vf2 + base + (size_t)k0 * D_DIM;
        *(int4*)as_ = cvt_f8(Vg + r0 * D_DIM + d0);
        *(int4*)bs_ = cvt_f8(Vg + (r0 + 1) * D_DIM + d0);
      }
      #pragma unroll
      for (int j = 0; j < 8; ++j) {
        int d = d0 + j;
        int blk = (r0 >> 3) ^ (d >> 3);
        unsigned pk = (unsigned)as_[j] | ((unsigned)bs_[j] << 16);
        *(unsigned*)&Vtlds[d * 72 + blk * 8 + (r0 & 7)] = pk;
      }
    }
    __syncthreads();

    f32x4 sc[2][4];
    #pragma unroll
    for (int mi = 0; mi < 2; ++mi)
      #pragma unroll
      for (int nt = 0; nt < 4; ++nt) sc[mi][nt] = zero4;
    #pragma unroll
    for (int nt = 0; nt < 4; ++nt) {
      bf16x8 kf0 = *(const bf16x8*)&QKlds[(nt * 16 + l15) * 72 + quad * 8];
      bf16x8 kf1 = *(const bf16x8*)&QKlds[(nt * 16 + l15) * 72 + 32 + quad * 8];
      #pragma unroll
      for (int mi = 0; mi < 2; ++mi) {
        sc[mi][nt] = mfma16(qf[mi][0], kf0, sc[mi][nt]);
        sc[mi][nt] = mfma16(qf[mi][1], kf1, sc[mi][nt]);
      }
    }

    #pragma unroll
    for (int mi = 0; mi < 2; ++mi) {
      #pragma unroll
      for (int nt = 0; nt < 4; ++nt) {
        #pragma unroll
        for (int reg = 0; reg < 4; ++reg) {
          int rg = q0 + wave * 32 + mi * 16 + quad * 4 + reg;
          size_t mix = (size_t)b * S_LEN * S_LEN + (size_t)rg * S_LEN + k0 + nt * 16 + l15;
          float mv = isb ? bf2f(((const unsigned short*)maskp)[mix])
                         : ((const float*)maskp)[mix];
          float y = sc[mi][nt][reg] * C1 - mv * C2;
          Plds2[(wave * 32 + mi * 16 + quad * 4 + reg) * 72 + nt * 16 + l15] =
              (short)f2bf(fexp2(y));
        }
      }
    }
    __syncthreads();

    #pragma unroll
    for (int kt = 0; kt < 2; ++kt) {
      bf16x8 pf[2];
      #pragma unroll
      for (int mi = 0; mi < 2; ++mi)
        pf[mi] = *(const bf16x8*)&Plds2[(wave * 32 + mi * 16 + l15) * 72 + kt * 32 + quad * 8];
      #pragma unroll
      for (int nt = 0; nt < 4; ++nt) {
        int d = nt * 16 + l15;
        int kb = (kt * 4 + quad) ^ (d >> 3);
        bf16x8 vf = *(const bf16x8*)&Vtlds[d * 72 + kb * 8];
        #pragma unroll
        for (int mi = 0; mi < 2; ++mi)
          acc_o[mi][nt] = mfma16(pf[mi], vf, acc_o[mi][nt]);
      }
      #pragma unroll
      for (int mi = 0; mi < 2; ++mi)
        acc_l[mi] = mfma16(pf[mi], onesB, acc_l[mi]);
    }
    __syncthreads();
  }

  #pragma unroll
  for (int mi = 0; mi < 2; ++mi) {
    #pragma unroll
    for (int reg = 0; reg < 4; ++reg) {
      float lv = __shfl(acc_l[mi][reg], lane & 48, 64);
      float inv = 1.0f / lv;
      #pragma unroll
      for (int nt = 0; nt < 4; ++nt) {
        float o = acc_o[mi][nt][reg] * inv;
        size_t idx = base + (size_t)(q0 + wave * 32 + mi * 16 + quad * 4 + reg) * D_DIM + nt * 16 + l15;
        if (isb) ((unsigned short*)Op)[idx] = f2bf(o);
        else     ((float*)Op)[idx] = o;
      }
    }
  }
}

extern "C" void kernel_launch(void* const* d_in, const int* in_sizes, int n_in,
                              void* d_out, int out_size, void* d_ws, size_t ws_size,
                              hipStream_t stream) {
  const void* Q = d_in[0];
  const void* K = d_in[1];
  const void* V = d_in[2];
  const void* M = d_in[3];

  dim3 block(256);
  const size_t bits_bytes = (size_t)2 * S_LEN * S_LEN / 8;          // 1 MB
  const size_t tens_bytes = (size_t)2 * 16 * S_LEN * D_DIM * 2;     // 8.4 MB bf16

  if (ws_size >= bits_bytes + 3 * tens_bytes) {
    char* ws = (char*)d_ws;
    ull* bits = (ull*)ws;
    unsigned short* Kf = (unsigned short*)(ws + bits_bytes);
    unsigned short* Vf = (unsigned short*)(ws + bits_bytes + tens_bytes);
    unsigned short* Qc = (unsigned short*)(ws + bits_bytes + 2 * tens_bytes);
    prep_all<<<dim3(SEG0 + SEG1 + SEG2 + SEG3), block, 0, stream>>>(
        M, K, V, Q, bits, Kf, Vf, Qc);
    attn_fast<<<dim3(512), block, 0, stream>>>(Qc, Q, Kf, K, Vf, bits, M, d_out);
  } else {
    attn_fallback<<<dim3(S_LEN / 128, 32), block, 0, stream>>>(Q, K, V, M, d_out);
  }
}